// Round 10
// baseline (58.167 us; speedup 1.0000x reference)
//
#include <hip/hip_runtime.h>
#include <hip/hip_bf16.h>

typedef __bf16 bf16x8 __attribute__((ext_vector_type(8)));
typedef float floatx4 __attribute__((ext_vector_type(4)));

#define BM 256
#define BN 128
#define BK 64
#define A_TILE (BM * BK)   // 16384 ushorts = 32 KB
#define B_TILE (BN * BK)   // 8192 ushorts  = 16 KB
#define EPS 1e-5f

// ---------------- f32 -> bf16 conversion (vectorized, grid-stride) ----------
__global__ void cvt_f32_to_bf16(const float* __restrict__ in,
                                ushort* __restrict__ out, int n4) {
    int i = blockIdx.x * blockDim.x + threadIdx.x;
    int stride = gridDim.x * blockDim.x;
    for (; i < n4; i += stride) {
        float4 v = reinterpret_cast<const float4*>(in)[i];
        ushort4 o;
        o.x = __builtin_bit_cast(unsigned short, __float2bfloat16(v.x));
        o.y = __builtin_bit_cast(unsigned short, __float2bfloat16(v.y));
        o.z = __builtin_bit_cast(unsigned short, __float2bfloat16(v.z));
        o.w = __builtin_bit_cast(unsigned short, __float2bfloat16(v.w));
        reinterpret_cast<ushort4*>(out)[i] = o;
    }
}

// ---------------- fold BN+scale into per-column alpha/bias ------------------
__global__ void bn_fold(const float* __restrict__ scale,
                        const float* __restrict__ mean,
                        const float* __restrict__ var,
                        const float* __restrict__ gamma,
                        const float* __restrict__ beta,
                        float* __restrict__ alpha,
                        float* __restrict__ bias, int n) {
    int i = blockIdx.x * blockDim.x + threadIdx.x;
    if (i < n) {
        float rs = rsqrtf(var[i] + EPS);
        float g = gamma[i] * rs;
        alpha[i] = scale[i] * g;
        bias[i]  = beta[i] - mean[i] * g;
    }
}

__device__ __forceinline__ void gload_lds16(const ushort* g, ushort* l) {
    __builtin_amdgcn_global_load_lds(
        (const __attribute__((address_space(1))) void*)g,
        (__attribute__((address_space(3))) void*)l, 16, 0, 0);
}

// ---------------- bf16 MFMA GEMM: 256x128, 4 waves of 128x64, BK=64 ---------
// C[m][n] = sum_k A[m][k]*B[n][k]; epilogue C = C*alpha[n] + bias[n].
//
// R9 post-mortem: with 8 waves of 64x64 (2.0 FLOP-ratio), per-tile LDS port
// demand (128KB reads + 48KB DMA ~ 1400 cyc) exceeds the MFMA floor
// (1242 cyc) -> LDS-bound at ~50% no matter the schedule. Fix: 4 waves of
// 128x64 (ratio 2.67) -> LDS ~1150 cyc < MFMA 1242 -> MFMA-bound possible.
//
// Per tile t (cur = t%3; setA holds frag(t,k0), read last iter):
//   LOADF(cur,k1)->setB; STAGE(t+2 -> (cur+2)%3)   // issue loads first
//   sched_barrier(0)                                // don't hoist MFMA above
//   MFMA(setA)            // 32 MFMA; overlaps setB ds_reads + DMA
//   MFMA(setB)            // lgkm-guarded on setB only
//   vmcnt(12)             // own 12 loads of tile t+1 landed
//   barrier               // invariant: all cur-reads consumed pre-barrier,
//                         // so staging (cur+2)=(cur-1) never races a reader
//   LOADF(nxt,k0)->setA   // tile t+1 resident
// Hazard audit: pending ds_reads at any barrier are only setA on nxt (issued
// after); staging target never has pending reads (R9 invariant preserved).
//
// LDS swizzle (T2, rule #21): phys chunk = logical chunk ^ (row&7), source
// pre-swizzled, reads XOR'd. R2/R4/R9 measured: conflicts = 0.
__global__ __launch_bounds__(256) void gemm_bf16_bn(
    const ushort* __restrict__ A,   // [M][K] bf16 bits
    const ushort* __restrict__ B,   // [N][K] bf16 bits
    const float* __restrict__ alpha,
    const float* __restrict__ bias,
    float* __restrict__ C, int M, int N, int K) {
    __shared__ ushort As[3 * A_TILE];   // 96 KB
    __shared__ ushort Bs[3 * B_TILE];   // 48 KB

    const int tid  = threadIdx.x;
    const int wid  = tid >> 6;
    const int lane = tid & 63;

    // bijective XCD-aware block swizzle (m204)
    const int nwg  = (int)gridDim.x;
    const int orig = (int)blockIdx.x;
    const int q = nwg >> 3, rr = nwg & 7;
    const int xcd = orig & 7;
    const int swz = ((xcd < rr) ? xcd * (q + 1) : rr * (q + 1) + (xcd - rr) * q)
                    + (orig >> 3);
    const int nTilesN = N / BN;
    const int brow = (swz / nTilesN) * BM;
    const int bcol = (swz % nTilesN) * BN;

    // 4 waves = 2M x 2N, each owns a 128x64 output sub-tile
    const int wr = (wid >> 1) * 128;
    const int wc = (wid & 1) * 64;
    const int fr = lane & 15;
    const int hi = lane >> 4;

    // fragment LDS offsets (ushort units), loop-invariant, swizzled
    int offA[2][8], offB[2][4];
#pragma unroll
    for (int s = 0; s < 2; ++s) {
#pragma unroll
        for (int m = 0; m < 8; ++m) {
            int row = wr + m * 16 + fr;                  // row&7 == fr&7
            offA[s][m] = row * BK + (((s * 4 + hi) ^ (fr & 7)) * 8);
        }
#pragma unroll
        for (int n = 0; n < 4; ++n) {
            int row = wc + n * 16 + fr;
            offB[s][n] = row * BK + (((s * 4 + hi) ^ (fr & 7)) * 8);
        }
    }

    // staging: 256 thr x 16B = 4 KB round = 32 rows of 128 B.
    // thread t: row = wid*8 + (lane>>3) in [0,32), phys chunk = lane&7;
    // source chunk pre-swizzled: (lane&7) ^ (lane>>3)  [row&7 == lane>>3]
    const int srow = wid * 8 + (lane >> 3);
    const int scol = ((lane & 7) ^ (lane >> 3)) * 8;
    const ushort* aSrc = A + (size_t)(brow + srow) * K + scol;
    const ushort* bSrc = B + (size_t)(bcol + srow) * K + scol;
    const int stDst = wid * 512;   // wave-uniform LDS base (HW adds lane*16B)

    floatx4 acc[8][4];
#pragma unroll
    for (int m = 0; m < 8; ++m)
#pragma unroll
        for (int n = 0; n < 4; ++n) acc[m][n] = (floatx4)0.0f;

    auto STAGE = [&](int koff, int bufsel) {   // 12 gloads: A 8 rounds, B 4
        ushort* da = As + bufsel * A_TILE + stDst;
        ushort* db = Bs + bufsel * B_TILE + stDst;
        const ushort* sa = aSrc + koff;
        const ushort* sb = bSrc + koff;
#pragma unroll
        for (int r = 0; r < 8; ++r)
            gload_lds16(sa + (size_t)(r * 32) * K, da + r * 2048);
#pragma unroll
        for (int r = 0; r < 4; ++r)
            gload_lds16(sb + (size_t)(r * 32) * K, db + r * 2048);
    };

    auto LOADF = [&](int bufsel, int s, bf16x8 (&af)[8], bf16x8 (&bf)[4]) {
        const ushort* pA = As + bufsel * A_TILE;
        const ushort* pB = Bs + bufsel * B_TILE;
#pragma unroll
        for (int m = 0; m < 8; ++m) af[m] = *(const bf16x8*)(pA + offA[s][m]);
#pragma unroll
        for (int n = 0; n < 4; ++n) bf[n] = *(const bf16x8*)(pB + offB[s][n]);
    };

    auto DOMFMA = [&](bf16x8 (&af)[8], bf16x8 (&bf)[4]) {
        __builtin_amdgcn_s_setprio(1);
#pragma unroll
        for (int m = 0; m < 8; ++m)
#pragma unroll
            for (int n = 0; n < 4; ++n)
                acc[m][n] = __builtin_amdgcn_mfma_f32_16x16x32_bf16(
                    af[m], bf[n], acc[m][n], 0, 0, 0);
        __builtin_amdgcn_s_setprio(0);
    };

    const int nK = K / BK;   // caller guarantees >= 4

    bf16x8 afA[8], bfA[4], afB[8], bfB[4];

    STAGE(0, 0);
    STAGE(BK, 1);
    asm volatile("s_waitcnt vmcnt(12)" ::: "memory");  // tile 0 landed (own)
    __builtin_amdgcn_s_barrier();                      // all waves' tile 0
    asm volatile("" ::: "memory");
    LOADF(0, 0, afA, bfA);                             // frag(0, k0)

    int cur = 0;
    for (int kt = 0; kt < nK; ++kt) {
        const bool st = (kt + 2 < nK);
        int tgt = cur + 2; if (tgt >= 3) tgt -= 3;
        LOADF(cur, 1, afB, bfB);            // issue frag(kt,k1) ds_reads
        if (st) STAGE((kt + 2) * BK, tgt);  // issue next-next tile DMA
        __builtin_amdgcn_sched_barrier(0);  // keep MFMA below the issues
        DOMFMA(afA, bfA);                   // k0 (regs ready; hides reads/DMA)
        DOMFMA(afB, bfB);                   // k1 (lgkm-guarded on setB)
        // all cur-reads consumed; tile boundary:
        if (kt + 1 < nK) {
            if (st) asm volatile("s_waitcnt vmcnt(12)" ::: "memory");
            else    asm volatile("s_waitcnt vmcnt(0)" ::: "memory");
            __builtin_amdgcn_s_barrier();   // tile kt+1 resident block-wide
            asm volatile("" ::: "memory");
            int nxt = cur + 1; if (nxt >= 3) nxt -= 3;
            LOADF(nxt, 0, afA, bfA);        // frag(kt+1, k0)
            cur = nxt;
        }
    }

    // epilogue: C/D layout col=lane&15, row=hi*4+j  [m89/m91 verified]
    float al[4], bi[4];
    const int ccol = bcol + wc + fr;
#pragma unroll
    for (int n = 0; n < 4; ++n) {
        al[n] = alpha[ccol + n * 16];
        bi[n] = bias[ccol + n * 16];
    }
    const int r0 = brow + wr + hi * 4;
#pragma unroll
    for (int m = 0; m < 8; ++m)
#pragma unroll
        for (int n = 0; n < 4; ++n)
#pragma unroll
            for (int j = 0; j < 4; ++j) {
                int row = r0 + m * 16 + j;
                int col = ccol + n * 16;
                C[(size_t)row * N + col] = acc[m][n][j] * al[n] + bi[n];
            }
}

// ---------------- safety fallback (fp32 vector, naive) ----------------------
__global__ void gemm_f32_naive(const float* __restrict__ A,
                               const float* __restrict__ B,
                               const float* __restrict__ scale,
                               const float* __restrict__ mean,
                               const float* __restrict__ var,
                               const float* __restrict__ gamma,
                               const float* __restrict__ beta,
                               float* __restrict__ C, int N, int K) {
    int o = blockIdx.x * blockDim.x + threadIdx.x;
    int b = blockIdx.y;
    if (o >= N) return;
    float s = 0.f;
    const float* a = A + (size_t)b * K;
    const float* w = B + (size_t)o * K;
    for (int k = 0; k < K; ++k) s += a[k] * w[k];
    float rs = rsqrtf(var[o] + EPS);
    float g = gamma[o] * rs;
    C[(size_t)b * N + o] = s * scale[o] * g + (beta[o] - mean[o] * g);
}

extern "C" void kernel_launch(void* const* d_in, const int* in_sizes, int n_in,
                              void* d_out, int out_size, void* d_ws, size_t ws_size,
                              hipStream_t stream) {
    const float* x     = (const float*)d_in[0];
    const float* w     = (const float*)d_in[1];
    const float* scale = (const float*)d_in[2];
    const float* mean  = (const float*)d_in[3];
    const float* var   = (const float*)d_in[4];
    const float* gamma = (const float*)d_in[5];
    const float* beta  = (const float*)d_in[6];
    float* out = (float*)d_out;

    const int OUT = in_sizes[2];
    const int IN  = in_sizes[1] / OUT;
    const int Bsz = in_sizes[0] / IN;

    const size_t xElems = (size_t)Bsz * IN;
    const size_t wElems = (size_t)OUT * IN;
    const size_t need = xElems * 2 + wElems * 2 + (size_t)OUT * 8;

    const bool tiled_ok = (Bsz % BM == 0) && (OUT % BN == 0) &&
                          (IN % BK == 0) && (IN / BK >= 4) &&
                          (ws_size >= need);

    if (!tiled_ok) {
        dim3 grid((OUT + 255) / 256, Bsz);
        gemm_f32_naive<<<grid, 256, 0, stream>>>(x, w, scale, mean, var, gamma,
                                                 beta, out, OUT, IN);
        return;
    }

    ushort* xb = (ushort*)d_ws;
    ushort* wb = xb + xElems;
    float* alpha = (float*)(wb + wElems);
    float* bias  = alpha + OUT;

    cvt_f32_to_bf16<<<2048, 256, 0, stream>>>(x, xb, (int)(xElems / 4));
    cvt_f32_to_bf16<<<2048, 256, 0, stream>>>(w, wb, (int)(wElems / 4));
    bn_fold<<<(OUT + 255) / 256, 256, 0, stream>>>(scale, mean, var, gamma, beta,
                                                   alpha, bias, OUT);

    dim3 grid((Bsz / BM) * (OUT / BN));
    gemm_bf16_bn<<<grid, 256, 0, stream>>>(xb, wb, alpha, bias, out, Bsz, OUT, IN);
}